// Round 8
// baseline (186.080 us; speedup 1.0000x reference)
//
#include <hip/hip_runtime.h>
#include <math.h>

#define N 8192
#define C_LOG2E 1.4426950408889634f
#define KBLK 8

typedef float v2f __attribute__((ext_vector_type(2)));
typedef unsigned long long u64;

// ---------- DPP full-wave (64-lane) sum; result valid in lane 63 ----------
__device__ __forceinline__ float dppWaveRed(float v) {
    float t;
    t = __int_as_float(__builtin_amdgcn_update_dpp(
        0, __float_as_int(v), 0x111, 0xf, 0xf, true)); v += t;  // row_shr:1
    t = __int_as_float(__builtin_amdgcn_update_dpp(
        0, __float_as_int(v), 0x112, 0xf, 0xf, true)); v += t;  // row_shr:2
    t = __int_as_float(__builtin_amdgcn_update_dpp(
        0, __float_as_int(v), 0x114, 0xf, 0xf, true)); v += t;  // row_shr:4
    t = __int_as_float(__builtin_amdgcn_update_dpp(
        0, __float_as_int(v), 0x118, 0xf, 0xf, true)); v += t;  // row_shr:8
    t = __int_as_float(__builtin_amdgcn_update_dpp(
        0, __float_as_int(v), 0x142, 0xa, 0xf, false)); v += t; // bcast15
    t = __int_as_float(__builtin_amdgcn_update_dpp(
        0, __float_as_int(v), 0x143, 0xc, 0xf, false)); v += t; // bcast31
    return v;
}

// ---------- one-time shuffle reductions (softmax_q / matvec) ----------
__device__ __forceinline__ float waveRedSum(float v) {
#pragma unroll
    for (int o = 32; o; o >>= 1) v += __shfl_xor(v, o);
    return v;
}
__device__ __forceinline__ float waveRedMax(float v) {
#pragma unroll
    for (int o = 32; o; o >>= 1) v = fmaxf(v, __shfl_xor(v, o));
    return v;
}
__device__ __forceinline__ float blockRedSum(float v, float* buf, int tid) {
    v = waveRedSum(v);
    if ((tid & 63) == 0) buf[tid >> 6] = v;
    __syncthreads();
    float r = buf[0];
#pragma unroll
    for (int j = 1; j < 16; ++j) r += buf[j];
    return r;
}
__device__ __forceinline__ float blockRedMax(float v, float* buf, int tid) {
    v = waveRedMax(v);
    if ((tid & 63) == 0) buf[tid >> 6] = v;
    __syncthreads();
    float r = buf[0];
#pragma unroll
    for (int j = 1; j < 16; ++j) r = fmaxf(r, buf[j]);
    return r;
}

// ---------- kernel 1: q = softmax(logits) + flag reset --------------------
// Runs before matvec/adam in stream order -> flags are zeroed every launch
// before the adam kernel can touch them (graph replays included).
__global__ __launch_bounds__(1024) void softmax_q_kernel(
    const float* __restrict__ logits, float* __restrict__ q,
    u64* __restrict__ flags) {
    __shared__ float bufA[16], bufB[16];
    const int tid = threadIdx.x;
    if (tid < 32) flags[tid] = 0ULL;
    float vals[8];
    float mx = -INFINITY;
#pragma unroll
    for (int k = 0; k < 8; ++k) {
        vals[k] = logits[tid + (k << 10)];
        mx = fmaxf(mx, vals[k]);
    }
    mx = blockRedMax(mx, bufA, tid);
    float E = 0.f;
#pragma unroll
    for (int k = 0; k < 8; ++k) {
        vals[k] = expf(vals[k] - mx);
        E += vals[k];
    }
    E = blockRedSum(E, bufB, tid);
#pragma unroll
    for (int k = 0; k < 8; ++k) q[tid + (k << 10)] = vals[k] / E;
}

// ---------- kernel 2: w = P @ q  (row-per-block matvec, HBM-roofline) -----
__global__ __launch_bounds__(256) void matvec_kernel(
    const float* __restrict__ P, const float* __restrict__ q,
    float* __restrict__ w) {
    const int row = blockIdx.x;
    const float4* __restrict__ Pr =
        reinterpret_cast<const float4*>(P + (size_t)row * N);
    const float4* __restrict__ q4 = reinterpret_cast<const float4*>(q);
    const int t = threadIdx.x;
    float acc = 0.f;
#pragma unroll
    for (int k = 0; k < 8; ++k) {
        float4 p = Pr[t + (k << 8)];
        float4 qq = q4[t + (k << 8)];
        acc = fmaf(p.x, qq.x, acc);
        acc = fmaf(p.y, qq.y, acc);
        acc = fmaf(p.z, qq.z, acc);
        acc = fmaf(p.w, qq.w, acc);
    }
    acc = waveRedSum(acc);
    __shared__ float lds[4];
    if ((t & 63) == 0) lds[t >> 6] = acc;
    __syncthreads();
    if (t == 0) w[row] = (lds[0] + lds[1]) + (lds[2] + lds[3]);
}

// ---------- exact f64 integer power (binary exponentiation) ----------
__device__ __forceinline__ double ipowd(double b, int e) {
    double r = 1.0;
    while (e) {
        if (e & 1) r *= b;
        b *= b;
        e >>= 1;
    }
    return r;
}

// ---------- grid-wide (8-block) reduction of (E, EW) ----------------------
// Intra-block: DPP wave sums -> 4 LDS partials -> 1 barrier -> every thread
// re-reduces (fixed order). Publish: tid0 stores 2 tag-embedded u64 words
// ((tag<<32)|float_bits) with relaxed agent-scope atomics -> payload rides
// atomically with the tag, no fences needed. Poll: all threads load all
// 16 words in parallel, retry until every tag == rid+1, then sum in fixed
// block order -> bit-identical result in every block/thread/replay.
// Slot parity rid&1: block b re-writes slot p only at rid+2, which it can
// reach only after consuming all rid+1 partials, which exist only after
// every reader consumed slot p at rid. Tags are exact-match, and flags are
// zeroed each launch by softmax_q_kernel, so stale values never match.
__device__ __forceinline__ v2f gridRedPair(float E, float EW, int rid,
                                           int b, int tid, int wid, int lane,
                                           v2f (*part)[4],
                                           u64* __restrict__ flags) {
    const int p = rid & 1;
    const unsigned want = (unsigned)(rid + 1);
    E = dppWaveRed(E);
    EW = dppWaveRed(EW);
    if (lane == 63) part[p][wid] = (v2f){E, EW};
    __syncthreads();
    const float4* p4 = reinterpret_cast<const float4*>(&part[p][0]);
    const float4 q0 = p4[0], q1 = p4[1];
    const v2f bp = ((v2f){q0.x, q0.y} + (v2f){q0.z, q0.w}) +
                   ((v2f){q1.x, q1.y} + (v2f){q1.z, q1.w});
    if (tid == 0) {
        const u64 w0 = ((u64)want << 32) | (u64)__float_as_uint(bp.x);
        const u64 w1 = ((u64)want << 32) | (u64)__float_as_uint(bp.y);
        __hip_atomic_store(&flags[p * 16 + b * 2 + 0], w0, __ATOMIC_RELAXED,
                           __HIP_MEMORY_SCOPE_AGENT);
        __hip_atomic_store(&flags[p * 16 + b * 2 + 1], w1, __ATOMIC_RELAXED,
                           __HIP_MEMORY_SCOPE_AGENT);
    }
    u64 a0[KBLK], a1[KBLK];
    bool ok;
    do {
        ok = true;
#pragma unroll
        for (int bb = 0; bb < KBLK; ++bb) {
            a0[bb] = __hip_atomic_load(&flags[p * 16 + bb * 2 + 0],
                                       __ATOMIC_RELAXED,
                                       __HIP_MEMORY_SCOPE_AGENT);
            a1[bb] = __hip_atomic_load(&flags[p * 16 + bb * 2 + 1],
                                       __ATOMIC_RELAXED,
                                       __HIP_MEMORY_SCOPE_AGENT);
        }
#pragma unroll
        for (int bb = 0; bb < KBLK; ++bb)
            ok = ok & ((unsigned)(a0[bb] >> 32) == want) &
                 ((unsigned)(a1[bb] >> 32) == want);
        if (!ok) __builtin_amdgcn_s_sleep(1);
    } while (!ok);
    v2f tot = (v2f){0.f, 0.f};
#pragma unroll
    for (int bb = 0; bb < KBLK; ++bb) {
        tot.x += __uint_as_float((unsigned)a0[bb]);
        tot.y += __uint_as_float((unsigned)a1[bb]);
    }
    return tot;
}

// ---------- kernel 3: Adam loop + finalize, 8 blocks x 256 threads --------
// Block b, thread t owns elements [b*1024 + 4t, +4) as 2 float2 vectors.
// State scaling as round 5/6: x' = x*log2e (exp -> one v_exp_f32),
// m' = 10*m, v' = 1000*v; all scales folded into exact-f64 table consts.
__global__ __launch_bounds__(256) void adam8_kernel(
    const float* __restrict__ w_g, const float* __restrict__ x0,
    const float* __restrict__ lam_p, const float* __restrict__ lr_p,
    const int* __restrict__ iters_p, float* __restrict__ out,
    u64* __restrict__ flags) {
    __shared__ v2f part[2][4];
    __shared__ float2 tab[128];  // (ctn, epsn2)

    const int tid = threadIdx.x;
    const int wid = tid >> 6;
    const int lane = tid & 63;
    const int b = blockIdx.x;
    const float lam = lam_p[0];
    const float lr = lr_p[0];
    const int iters = iters_p[0];

    // parallel exact bias-correction table (first used after a barrier)
    if (tid < iters && tid < 128) {
        const float d1 = (float)(1.0 - ipowd(0.9, tid + 1));
        const float d2 = (float)(1.0 - ipowd(0.999, tid + 1));
        const float sd2 = sqrtf(d2);
        const float ct = lr * sd2 / d1;
        const float se = C_LOG2E * 1e-8f * sd2;
        tab[tid] = make_float2(C_LOG2E * ct * sqrtf(10.f), 1000.f * se * se);
    }

    const int gv = (b << 8) + tid;  // float4 index; elements 4*gv..4*gv+3
    v2f x[2], m[2], v[2], wv[2];
    {
        const float4 a = reinterpret_cast<const float4*>(x0)[gv];
        const float4 c = reinterpret_cast<const float4*>(w_g)[gv];
        x[0] = (v2f){a.x * C_LOG2E, a.y * C_LOG2E};
        x[1] = (v2f){a.z * C_LOG2E, a.w * C_LOG2E};
        wv[0] = (v2f){c.x, c.y};
        wv[1] = (v2f){c.z, c.w};
    }
    m[0] = m[1] = (v2f){0.f, 0.f};
    v[0] = v[1] = (v2f){0.f, 0.f};

    const v2f lam2 = (v2f){lam, lam};
    const v2f c09 = (v2f){0.9f, 0.9f};
    const v2f c0999 = (v2f){0.999f, 0.999f};

    for (int rid = 0; rid < iters; ++rid) {
        v2f e[2];
        e[0] = (v2f){__builtin_amdgcn_exp2f(x[0].x),
                     __builtin_amdgcn_exp2f(x[0].y)};
        e[1] = (v2f){__builtin_amdgcn_exp2f(x[1].x),
                     __builtin_amdgcn_exp2f(x[1].y)};
        const v2f E2 = e[0] + e[1];
        const v2f EW2 = e[0] * wv[0] + e[1] * wv[1];
        // hoisted off the post-reduction critical path
        v2f lx[2], m9[2], v9[2];
        lx[0] = lam2 * x[0]; lx[1] = lam2 * x[1];
        m9[0] = c09 * m[0]; m9[1] = c09 * m[1];
        v9[0] = c0999 * v[0]; v9[1] = c0999 * v[1];

        const v2f tot = gridRedPair(E2.x + E2.y, EW2.x + EW2.y, rid, b, tid,
                                    wid, lane, part, flags);
        const float rE = __builtin_amdgcn_rcpf(tot.x);
        const float rEc = rE * C_LOG2E;
        const float frEc = (tot.y * rE) * rEc;
        const float2 ct = tab[rid];
        const v2f u2 = (v2f){rEc, rEc};
        const v2f fu2 = (v2f){frEc, frEc};
        const v2f ctx2 = (v2f){ct.x, ct.x};
        const v2f eps2 = (v2f){ct.y, ct.y};
#pragma unroll
        for (int j = 0; j < 2; ++j) {
            const v2f t = fu2 - wv[j] * u2;   // 1 pk_fma
            const v2f g = e[j] * t + lx[j];   // 1 pk_fma
            m[j] = m9[j] + g;                 // 1 pk_add (x10 scale)
            v[j] = v9[j] + g * g;             // 1 pk_fma (x1000 scale)
            const v2f ve = v[j] + eps2;       // 1 pk_add
            const v2f ir = (v2f){__builtin_amdgcn_rsqf(ve.x),
                                 __builtin_amdgcn_rsqf(ve.y)};
            x[j] = x[j] - (m[j] * ctx2) * ir; // pk_mul + pk_fma
        }
    }

    // ---- finalize: g = s*(w-f)/lam at final x; br = (x-g)+g ----
    {
        v2f e[2];
        e[0] = (v2f){__builtin_amdgcn_exp2f(x[0].x),
                     __builtin_amdgcn_exp2f(x[0].y)};
        e[1] = (v2f){__builtin_amdgcn_exp2f(x[1].x),
                     __builtin_amdgcn_exp2f(x[1].y)};
        const v2f E2 = e[0] + e[1];
        const v2f EW2 = e[0] * wv[0] + e[1] * wv[1];
        const v2f tot = gridRedPair(E2.x + E2.y, EW2.x + EW2.y, iters, b, tid,
                                    wid, lane, part, flags);
        const float rE = 1.0f / tot.x;  // precise one-time
        const float f = tot.y * rE;

        const float invc = 1.0f / C_LOG2E;
        float br[4];
#pragma unroll
        for (int j = 0; j < 2; ++j) {
#pragma unroll
            for (int h = 0; h < 2; ++h) {
                const float ee = h ? e[j].y : e[j].x;
                const float ww = h ? wv[j].y : wv[j].x;
                const float xx = (h ? x[j].y : x[j].x) * invc;  // back to x
                const float s = ee * rE;
                const float g = (s * (ww - f)) / lam;  // one-time IEEE div
                br[2 * j + h] = (xx - g) + g;
            }
        }

        // r = softmax(br) . w  (precise exp for the one-time output)
        v2f E3 = (v2f){0.f, 0.f}, EW3 = (v2f){0.f, 0.f};
#pragma unroll
        for (int j = 0; j < 2; ++j) {
            const v2f eb = (v2f){__expf(br[2 * j]), __expf(br[2 * j + 1])};
            E3 += eb;
            EW3 += eb * wv[j];
        }
        const v2f tot3 = gridRedPair(E3.x + E3.y, EW3.x + EW3.y, iters + 1, b,
                                     tid, wid, lane, part, flags);
        const float r = tot3.y / tot3.x;  // precise one-time

        if (b == 0 && tid == 0) out[0] = r;
#pragma unroll
        for (int k = 0; k < 4; ++k) out[1 + (gv << 2) + k] = br[k];
    }
}

extern "C" void kernel_launch(void* const* d_in, const int* in_sizes, int n_in,
                              void* d_out, int out_size, void* d_ws,
                              size_t ws_size, hipStream_t stream) {
    const float* logits = (const float*)d_in[0];   // (8192,)
    const float* P      = (const float*)d_in[1];   // (8192, 8192)
    const float* x0     = (const float*)d_in[2];   // (8192,)
    const float* lam    = (const float*)d_in[3];   // scalar
    const float* lr     = (const float*)d_in[4];   // scalar
    const int*   iters  = (const int*)d_in[5];     // scalar int
    float* out = (float*)d_out;                    // [0]=r, [1..8192]=br

    float* q = (float*)d_ws;                       // 8192 floats
    float* w = q + N;                              // 8192 floats
    u64* flags = (u64*)((char*)d_ws + 2 * N * sizeof(float));  // 32 u64

    softmax_q_kernel<<<1, 1024, 0, stream>>>(logits, q, flags);
    matvec_kernel<<<N, 256, 0, stream>>>(P, q, w);
    adam8_kernel<<<KBLK, 256, 0, stream>>>(w, x0, lam, lr, iters, out, flags);
}

// Round 9
// 184.826 us; speedup vs baseline: 1.0068x; 1.0068x over previous
//
#include <hip/hip_runtime.h>
#include <math.h>

#define N 8192
#define C_LOG2E 1.4426950408889634f
#define KBLK 8

typedef float v2f __attribute__((ext_vector_type(2)));
typedef unsigned long long u64;

// ---------- DPP full-wave (64-lane) sum; result valid in lane 63 ----------
__device__ __forceinline__ float dppWaveRed(float v) {
    float t;
    t = __int_as_float(__builtin_amdgcn_update_dpp(
        0, __float_as_int(v), 0x111, 0xf, 0xf, true)); v += t;  // row_shr:1
    t = __int_as_float(__builtin_amdgcn_update_dpp(
        0, __float_as_int(v), 0x112, 0xf, 0xf, true)); v += t;  // row_shr:2
    t = __int_as_float(__builtin_amdgcn_update_dpp(
        0, __float_as_int(v), 0x114, 0xf, 0xf, true)); v += t;  // row_shr:4
    t = __int_as_float(__builtin_amdgcn_update_dpp(
        0, __float_as_int(v), 0x118, 0xf, 0xf, true)); v += t;  // row_shr:8
    t = __int_as_float(__builtin_amdgcn_update_dpp(
        0, __float_as_int(v), 0x142, 0xa, 0xf, false)); v += t; // bcast15
    t = __int_as_float(__builtin_amdgcn_update_dpp(
        0, __float_as_int(v), 0x143, 0xc, 0xf, false)); v += t; // bcast31
    return v;
}

// ---------- one-time shuffle reductions (softmax_q / matvec) ----------
__device__ __forceinline__ float waveRedSum(float v) {
#pragma unroll
    for (int o = 32; o; o >>= 1) v += __shfl_xor(v, o);
    return v;
}
__device__ __forceinline__ float waveRedMax(float v) {
#pragma unroll
    for (int o = 32; o; o >>= 1) v = fmaxf(v, __shfl_xor(v, o));
    return v;
}
__device__ __forceinline__ float blockRedSum(float v, float* buf, int tid) {
    v = waveRedSum(v);
    if ((tid & 63) == 0) buf[tid >> 6] = v;
    __syncthreads();
    float r = buf[0];
#pragma unroll
    for (int j = 1; j < 16; ++j) r += buf[j];
    return r;
}
__device__ __forceinline__ float blockRedMax(float v, float* buf, int tid) {
    v = waveRedMax(v);
    if ((tid & 63) == 0) buf[tid >> 6] = v;
    __syncthreads();
    float r = buf[0];
#pragma unroll
    for (int j = 1; j < 16; ++j) r = fmaxf(r, buf[j]);
    return r;
}

// ---------- kernel 1: q = softmax(logits) + flag reset --------------------
// Runs before matvec/adam in stream order -> flags are zeroed every launch
// before the adam kernel can touch them (graph replays included).
__global__ __launch_bounds__(1024) void softmax_q_kernel(
    const float* __restrict__ logits, float* __restrict__ q,
    u64* __restrict__ flags) {
    __shared__ float bufA[16], bufB[16];
    const int tid = threadIdx.x;
    if (tid < 32) flags[tid] = 0ULL;
    float vals[8];
    float mx = -INFINITY;
#pragma unroll
    for (int k = 0; k < 8; ++k) {
        vals[k] = logits[tid + (k << 10)];
        mx = fmaxf(mx, vals[k]);
    }
    mx = blockRedMax(mx, bufA, tid);
    float E = 0.f;
#pragma unroll
    for (int k = 0; k < 8; ++k) {
        vals[k] = expf(vals[k] - mx);
        E += vals[k];
    }
    E = blockRedSum(E, bufB, tid);
#pragma unroll
    for (int k = 0; k < 8; ++k) q[tid + (k << 10)] = vals[k] / E;
}

// ---------- kernel 2: w = P @ q  (row-per-block matvec, HBM-roofline) -----
__global__ __launch_bounds__(256) void matvec_kernel(
    const float* __restrict__ P, const float* __restrict__ q,
    float* __restrict__ w) {
    const int row = blockIdx.x;
    const float4* __restrict__ Pr =
        reinterpret_cast<const float4*>(P + (size_t)row * N);
    const float4* __restrict__ q4 = reinterpret_cast<const float4*>(q);
    const int t = threadIdx.x;
    float acc = 0.f;
#pragma unroll
    for (int k = 0; k < 8; ++k) {
        float4 p = Pr[t + (k << 8)];
        float4 qq = q4[t + (k << 8)];
        acc = fmaf(p.x, qq.x, acc);
        acc = fmaf(p.y, qq.y, acc);
        acc = fmaf(p.z, qq.z, acc);
        acc = fmaf(p.w, qq.w, acc);
    }
    acc = waveRedSum(acc);
    __shared__ float lds[4];
    if ((t & 63) == 0) lds[t >> 6] = acc;
    __syncthreads();
    if (t == 0) w[row] = (lds[0] + lds[1]) + (lds[2] + lds[3]);
}

// ---------- exact f64 integer power (binary exponentiation) ----------
__device__ __forceinline__ double ipowd(double b, int e) {
    double r = 1.0;
    while (e) {
        if (e & 1) r *= b;
        b *= b;
        e >>= 1;
    }
    return r;
}

// ---------- grid-wide (8-block) reduction of (E, EW) ----------------------
// Intra-block: DPP wave sums -> 4 LDS partials -> 1 barrier -> every thread
// re-reduces (fixed order). Publish: tid0 stores 2 tag-embedded u64 words
// ((tag<<32)|float_bits) with relaxed agent-scope atomics -> payload rides
// atomically with the tag, no fences needed. Poll: all threads load all
// 16 words in parallel, retry until every tag == rid+1, then sum in fixed
// block order -> bit-identical result in every block/thread/replay.
// Slot parity rid&1: block b re-writes slot p only at rid+2, which it can
// reach only after consuming all rid+1 partials, which exist only after
// every reader consumed slot p at rid. Tags are exact-match, and flags are
// zeroed each launch by softmax_q_kernel, so stale values never match.
__device__ __forceinline__ v2f gridRedPair(float E, float EW, int rid,
                                           int b, int tid, int wid, int lane,
                                           v2f (*part)[4],
                                           u64* __restrict__ flags) {
    const int p = rid & 1;
    const unsigned want = (unsigned)(rid + 1);
    E = dppWaveRed(E);
    EW = dppWaveRed(EW);
    if (lane == 63) part[p][wid] = (v2f){E, EW};
    __syncthreads();
    const float4* p4 = reinterpret_cast<const float4*>(&part[p][0]);
    const float4 q0 = p4[0], q1 = p4[1];
    const v2f bp = ((v2f){q0.x, q0.y} + (v2f){q0.z, q0.w}) +
                   ((v2f){q1.x, q1.y} + (v2f){q1.z, q1.w});
    if (tid == 0) {
        const u64 w0 = ((u64)want << 32) | (u64)__float_as_uint(bp.x);
        const u64 w1 = ((u64)want << 32) | (u64)__float_as_uint(bp.y);
        __hip_atomic_store(&flags[p * 16 + b * 2 + 0], w0, __ATOMIC_RELAXED,
                           __HIP_MEMORY_SCOPE_AGENT);
        __hip_atomic_store(&flags[p * 16 + b * 2 + 1], w1, __ATOMIC_RELAXED,
                           __HIP_MEMORY_SCOPE_AGENT);
    }
    u64 a0[KBLK], a1[KBLK];
    bool ok;
    do {
        ok = true;
#pragma unroll
        for (int bb = 0; bb < KBLK; ++bb) {
            a0[bb] = __hip_atomic_load(&flags[p * 16 + bb * 2 + 0],
                                       __ATOMIC_RELAXED,
                                       __HIP_MEMORY_SCOPE_AGENT);
            a1[bb] = __hip_atomic_load(&flags[p * 16 + bb * 2 + 1],
                                       __ATOMIC_RELAXED,
                                       __HIP_MEMORY_SCOPE_AGENT);
        }
#pragma unroll
        for (int bb = 0; bb < KBLK; ++bb)
            ok = ok & ((unsigned)(a0[bb] >> 32) == want) &
                 ((unsigned)(a1[bb] >> 32) == want);
        if (!ok) __builtin_amdgcn_s_sleep(1);
    } while (!ok);
    v2f tot = (v2f){0.f, 0.f};
#pragma unroll
    for (int bb = 0; bb < KBLK; ++bb) {
        tot.x += __uint_as_float((unsigned)a0[bb]);
        tot.y += __uint_as_float((unsigned)a1[bb]);
    }
    return tot;
}

// ---------- kernel 3: Adam loop + finalize, 8 blocks x 256 threads --------
// Block b, thread t owns elements [b*1024 + 4t, +4) as 2 float2 vectors.
// State scaling as round 5/6: x' = x*log2e (exp -> one v_exp_f32),
// m' = 10*m, v' = 1000*v; all scales folded into exact-f64 table consts.
__global__ __launch_bounds__(256) void adam8_kernel(
    const float* __restrict__ w_g, const float* __restrict__ x0,
    const float* __restrict__ lam_p, const float* __restrict__ lr_p,
    const int* __restrict__ iters_p, float* __restrict__ out,
    u64* __restrict__ flags) {
    __shared__ v2f part[2][4];
    __shared__ float2 tab[128];  // (ctn, epsn2)

    const int tid = threadIdx.x;
    const int wid = tid >> 6;
    const int lane = tid & 63;
    const int b = blockIdx.x;
    const float lam = lam_p[0];
    const float lr = lr_p[0];
    const int iters = iters_p[0];

    // parallel exact bias-correction table (first used after a barrier)
    if (tid < iters && tid < 128) {
        const float d1 = (float)(1.0 - ipowd(0.9, tid + 1));
        const float d2 = (float)(1.0 - ipowd(0.999, tid + 1));
        const float sd2 = sqrtf(d2);
        const float ct = lr * sd2 / d1;
        const float se = C_LOG2E * 1e-8f * sd2;
        tab[tid] = make_float2(C_LOG2E * ct * sqrtf(10.f), 1000.f * se * se);
    }

    const int gv = (b << 8) + tid;  // float4 index; elements 4*gv..4*gv+3
    v2f x[2], m[2], v[2], wv[2];
    {
        const float4 a = reinterpret_cast<const float4*>(x0)[gv];
        const float4 c = reinterpret_cast<const float4*>(w_g)[gv];
        x[0] = (v2f){a.x * C_LOG2E, a.y * C_LOG2E};
        x[1] = (v2f){a.z * C_LOG2E, a.w * C_LOG2E};
        wv[0] = (v2f){c.x, c.y};
        wv[1] = (v2f){c.z, c.w};
    }
    m[0] = m[1] = (v2f){0.f, 0.f};
    v[0] = v[1] = (v2f){0.f, 0.f};

    const v2f lam2 = (v2f){lam, lam};
    const v2f c09 = (v2f){0.9f, 0.9f};
    const v2f c0999 = (v2f){0.999f, 0.999f};

    for (int rid = 0; rid < iters; ++rid) {
        v2f e[2];
        e[0] = (v2f){__builtin_amdgcn_exp2f(x[0].x),
                     __builtin_amdgcn_exp2f(x[0].y)};
        e[1] = (v2f){__builtin_amdgcn_exp2f(x[1].x),
                     __builtin_amdgcn_exp2f(x[1].y)};
        const v2f E2 = e[0] + e[1];
        const v2f EW2 = e[0] * wv[0] + e[1] * wv[1];
        // hoisted off the post-reduction critical path
        v2f lx[2], m9[2], v9[2];
        lx[0] = lam2 * x[0]; lx[1] = lam2 * x[1];
        m9[0] = c09 * m[0]; m9[1] = c09 * m[1];
        v9[0] = c0999 * v[0]; v9[1] = c0999 * v[1];

        const v2f tot = gridRedPair(E2.x + E2.y, EW2.x + EW2.y, rid, b, tid,
                                    wid, lane, part, flags);
        const float rE = __builtin_amdgcn_rcpf(tot.x);
        const float rEc = rE * C_LOG2E;
        const float frEc = (tot.y * rE) * rEc;
        const float2 ct = tab[rid];
        const v2f u2 = (v2f){rEc, rEc};
        const v2f fu2 = (v2f){frEc, frEc};
        const v2f ctx2 = (v2f){ct.x, ct.x};
        const v2f eps2 = (v2f){ct.y, ct.y};
#pragma unroll
        for (int j = 0; j < 2; ++j) {
            const v2f t = fu2 - wv[j] * u2;   // 1 pk_fma
            const v2f g = e[j] * t + lx[j];   // 1 pk_fma
            m[j] = m9[j] + g;                 // 1 pk_add (x10 scale)
            v[j] = v9[j] + g * g;             // 1 pk_fma (x1000 scale)
            const v2f ve = v[j] + eps2;       // 1 pk_add
            const v2f ir = (v2f){__builtin_amdgcn_rsqf(ve.x),
                                 __builtin_amdgcn_rsqf(ve.y)};
            x[j] = x[j] - (m[j] * ctx2) * ir; // pk_mul + pk_fma
        }
    }

    // ---- finalize: g = s*(w-f)/lam at final x; br = (x-g)+g ----
    {
        v2f e[2];
        e[0] = (v2f){__builtin_amdgcn_exp2f(x[0].x),
                     __builtin_amdgcn_exp2f(x[0].y)};
        e[1] = (v2f){__builtin_amdgcn_exp2f(x[1].x),
                     __builtin_amdgcn_exp2f(x[1].y)};
        const v2f E2 = e[0] + e[1];
        const v2f EW2 = e[0] * wv[0] + e[1] * wv[1];
        const v2f tot = gridRedPair(E2.x + E2.y, EW2.x + EW2.y, iters, b, tid,
                                    wid, lane, part, flags);
        const float rE = 1.0f / tot.x;  // precise one-time
        const float f = tot.y * rE;

        const float invc = 1.0f / C_LOG2E;
        float br[4];
#pragma unroll
        for (int j = 0; j < 2; ++j) {
#pragma unroll
            for (int h = 0; h < 2; ++h) {
                const float ee = h ? e[j].y : e[j].x;
                const float ww = h ? wv[j].y : wv[j].x;
                const float xx = (h ? x[j].y : x[j].x) * invc;  // back to x
                const float s = ee * rE;
                const float g = (s * (ww - f)) / lam;  // one-time IEEE div
                br[2 * j + h] = (xx - g) + g;
            }
        }

        // r = softmax(br) . w  (precise exp for the one-time output)
        v2f E3 = (v2f){0.f, 0.f}, EW3 = (v2f){0.f, 0.f};
#pragma unroll
        for (int j = 0; j < 2; ++j) {
            const v2f eb = (v2f){__expf(br[2 * j]), __expf(br[2 * j + 1])};
            E3 += eb;
            EW3 += eb * wv[j];
        }
        const v2f tot3 = gridRedPair(E3.x + E3.y, EW3.x + EW3.y, iters + 1, b,
                                     tid, wid, lane, part, flags);
        const float r = tot3.y / tot3.x;  // precise one-time

        if (b == 0 && tid == 0) out[0] = r;
#pragma unroll
        for (int k = 0; k < 4; ++k) out[1 + (gv << 2) + k] = br[k];
    }
}

extern "C" void kernel_launch(void* const* d_in, const int* in_sizes, int n_in,
                              void* d_out, int out_size, void* d_ws,
                              size_t ws_size, hipStream_t stream) {
    const float* logits = (const float*)d_in[0];   // (8192,)
    const float* P      = (const float*)d_in[1];   // (8192, 8192)
    const float* x0     = (const float*)d_in[2];   // (8192,)
    const float* lam    = (const float*)d_in[3];   // scalar
    const float* lr     = (const float*)d_in[4];   // scalar
    const int*   iters  = (const int*)d_in[5];     // scalar int
    float* out = (float*)d_out;                    // [0]=r, [1..8192]=br

    float* q = (float*)d_ws;                       // 8192 floats
    float* w = q + N;                              // 8192 floats
    u64* flags = (u64*)((char*)d_ws + 2 * N * sizeof(float));  // 32 u64

    softmax_q_kernel<<<1, 1024, 0, stream>>>(logits, q, flags);
    matvec_kernel<<<N, 256, 0, stream>>>(P, q, w);
    adam8_kernel<<<KBLK, 256, 0, stream>>>(w, x0, lam, lr, iters, out, flags);
}

// Round 10
// 108.781 us; speedup vs baseline: 1.7106x; 1.6991x over previous
//
#include <hip/hip_runtime.h>
#include <math.h>

#define N 8192
#define C_LOG2E 1.4426950408889634f

typedef float v2f __attribute__((ext_vector_type(2)));

// ---------- DPP full-wave (64-lane) sum; result valid in lane 63 ----------
__device__ __forceinline__ float dppWaveRed(float v) {
    float t;
    t = __int_as_float(__builtin_amdgcn_update_dpp(
        0, __float_as_int(v), 0x111, 0xf, 0xf, true)); v += t;  // row_shr:1
    t = __int_as_float(__builtin_amdgcn_update_dpp(
        0, __float_as_int(v), 0x112, 0xf, 0xf, true)); v += t;  // row_shr:2
    t = __int_as_float(__builtin_amdgcn_update_dpp(
        0, __float_as_int(v), 0x114, 0xf, 0xf, true)); v += t;  // row_shr:4
    t = __int_as_float(__builtin_amdgcn_update_dpp(
        0, __float_as_int(v), 0x118, 0xf, 0xf, true)); v += t;  // row_shr:8
    t = __int_as_float(__builtin_amdgcn_update_dpp(
        0, __float_as_int(v), 0x142, 0xa, 0xf, false)); v += t; // bcast15
    t = __int_as_float(__builtin_amdgcn_update_dpp(
        0, __float_as_int(v), 0x143, 0xc, 0xf, false)); v += t; // bcast31
    return v;
}
// Inclusive 16-lane row scan; lane 15 (mod 16) holds the row sum.
__device__ __forceinline__ float dppRowRed16(float v) {
    float t;
    t = __int_as_float(__builtin_amdgcn_update_dpp(
        0, __float_as_int(v), 0x111, 0xf, 0xf, true)); v += t;
    t = __int_as_float(__builtin_amdgcn_update_dpp(
        0, __float_as_int(v), 0x112, 0xf, 0xf, true)); v += t;
    t = __int_as_float(__builtin_amdgcn_update_dpp(
        0, __float_as_int(v), 0x114, 0xf, 0xf, true)); v += t;
    t = __int_as_float(__builtin_amdgcn_update_dpp(
        0, __float_as_int(v), 0x118, 0xf, 0xf, true)); v += t;
    return v;
}
__device__ __forceinline__ float readlane15(float v) {
    return __uint_as_float(
        (unsigned)__builtin_amdgcn_readlane(__float_as_uint(v), 15));
}

// ---------- one-time shuffle reductions (softmax_q / matvec) ----------
__device__ __forceinline__ float waveRedSum(float v) {
#pragma unroll
    for (int o = 32; o; o >>= 1) v += __shfl_xor(v, o);
    return v;
}
__device__ __forceinline__ float waveRedMax(float v) {
#pragma unroll
    for (int o = 32; o; o >>= 1) v = fmaxf(v, __shfl_xor(v, o));
    return v;
}
__device__ __forceinline__ float blockRedSum(float v, float* buf, int tid) {
    v = waveRedSum(v);
    if ((tid & 63) == 0) buf[tid >> 6] = v;
    __syncthreads();
    float r = buf[0];
#pragma unroll
    for (int j = 1; j < 16; ++j) r += buf[j];
    return r;
}
__device__ __forceinline__ float blockRedMax(float v, float* buf, int tid) {
    v = waveRedMax(v);
    if ((tid & 63) == 0) buf[tid >> 6] = v;
    __syncthreads();
    float r = buf[0];
#pragma unroll
    for (int j = 1; j < 16; ++j) r = fmaxf(r, buf[j]);
    return r;
}

// ---------- kernel 1: q = softmax(logits) (one-time, precise) -------------
__global__ __launch_bounds__(1024) void softmax_q_kernel(
    const float* __restrict__ logits, float* __restrict__ q) {
    __shared__ float bufA[16], bufB[16];
    const int tid = threadIdx.x;
    float vals[8];
    float mx = -INFINITY;
#pragma unroll
    for (int k = 0; k < 8; ++k) {
        vals[k] = logits[tid + (k << 10)];
        mx = fmaxf(mx, vals[k]);
    }
    mx = blockRedMax(mx, bufA, tid);
    float E = 0.f;
#pragma unroll
    for (int k = 0; k < 8; ++k) {
        vals[k] = expf(vals[k] - mx);
        E += vals[k];
    }
    E = blockRedSum(E, bufB, tid);
#pragma unroll
    for (int k = 0; k < 8; ++k) q[tid + (k << 10)] = vals[k] / E;
}

// ---------- kernel 2: w = P @ q  (row-per-block matvec, HBM-roofline) -----
__global__ __launch_bounds__(256) void matvec_kernel(
    const float* __restrict__ P, const float* __restrict__ q,
    float* __restrict__ w) {
    const int row = blockIdx.x;
    const float4* __restrict__ Pr =
        reinterpret_cast<const float4*>(P + (size_t)row * N);
    const float4* __restrict__ q4 = reinterpret_cast<const float4*>(q);
    const int t = threadIdx.x;
    float acc = 0.f;
#pragma unroll
    for (int k = 0; k < 8; ++k) {
        float4 p = Pr[t + (k << 8)];
        float4 qq = q4[t + (k << 8)];
        acc = fmaf(p.x, qq.x, acc);
        acc = fmaf(p.y, qq.y, acc);
        acc = fmaf(p.z, qq.z, acc);
        acc = fmaf(p.w, qq.w, acc);
    }
    acc = waveRedSum(acc);
    __shared__ float lds[4];
    if ((t & 63) == 0) lds[t >> 6] = acc;
    __syncthreads();
    if (t == 0) w[row] = (lds[0] + lds[1]) + (lds[2] + lds[3]);
}

// ---------- exact f64 integer power (binary exponentiation) ----------
__device__ __forceinline__ double ipowd(double b, int e) {
    double r = 1.0;
    while (e) {
        if (e & 1) r *= b;
        b *= b;
        e >>= 1;
    }
    return r;
}

// ---------- adam: ONE-barrier block reduction, barrier-free tail ----------
// dppWaveRed -> lane63 writes part[wid] -> __syncthreads -> EVERY thread:
// one broadcast ds_read_b64 of part[lane&15] (same-address lanes merge,
// conflict-free), 4-step dppRowRed16 per value, readlane(15) -> uniform
// totals in SGPRs. No second barrier, no serialized wave0 phase, and only
// ~11 extra instrs/thread. Deterministic (fixed order everywhere).
// Race safety with ONE barrier/call: caller alternates parity buffers; a
// write to slot p at call i+2 happens after barrier(i+1), which orders it
// after all reads of slot p at call i.
__device__ __forceinline__ v2f blockRed1B(float E, float EW, v2f* partp,
                                          int wid, int lane) {
    E = dppWaveRed(E);
    EW = dppWaveRed(EW);
    if (lane == 63) partp[wid] = (v2f){E, EW};
    __syncthreads();
    const v2f pv = partp[lane & 15];
    const float E16 = dppRowRed16(pv.x);
    const float W16 = dppRowRed16(pv.y);
    return (v2f){readlane15(E16), readlane15(W16)};
}

// ---------- kernel 3: Adam loop + implicit-gradient finalize --------------
// 1024 threads, 16 waves, one CU. Thread t owns elements [8t, 8t+8) as 4
// float2 ext-vectors (packed fp32). State scaling (verified r5):
//   x' = x*log2e (exp -> one v_exp_f32), m' = 10c*m, v' = 1000c^2*v;
//   step' = ctn * m' * rsq(v' + epsn2),
//   ctn = c*ct*sqrt(10), epsn2 = 1000*(c*eps_t)^2,
//   ct = lr*sqrt(d2)/d1, eps_t = 1e-8*sqrt(d2)   (exact f64 table).
__global__ __launch_bounds__(1024) void adam_kernel(
    const float* __restrict__ w_g, const float* __restrict__ x0,
    const float* __restrict__ lam_p, const float* __restrict__ lr_p,
    const int* __restrict__ iters_p, float* __restrict__ out) {
    __shared__ v2f part[2][16];
    __shared__ float2 tab[128];  // (ctn, epsn2)

    const int tid = threadIdx.x;
    const int wid = tid >> 6;
    const int lane = tid & 63;
    const float lam = lam_p[0];
    const float lr = lr_p[0];
    const int iters = iters_p[0];

    // parallel exact bias-correction table (first read is after iter-0's
    // reduction barrier -> ordered)
    if (tid < iters && tid < 128) {
        const float d1 = (float)(1.0 - ipowd(0.9, tid + 1));
        const float d2 = (float)(1.0 - ipowd(0.999, tid + 1));
        const float sd2 = sqrtf(d2);
        const float ct = lr * sd2 / d1;
        const float se = C_LOG2E * 1e-8f * sd2;
        tab[tid] = make_float2(C_LOG2E * ct * sqrtf(10.f), 1000.f * se * se);
    }

    // ---- registers: blocked mapping, float4 loads; x kept log2e-scaled ----
    v2f x[4], m[4], v[4], wv[4];
    const float4* __restrict__ x04 = reinterpret_cast<const float4*>(x0);
    const float4* __restrict__ wg4 = reinterpret_cast<const float4*>(w_g);
#pragma unroll
    for (int h = 0; h < 2; ++h) {
        const float4 a = x04[(tid << 1) | h];
        const float4 b = wg4[(tid << 1) | h];
        x[2 * h + 0] = (v2f){a.x * C_LOG2E, a.y * C_LOG2E};
        x[2 * h + 1] = (v2f){a.z * C_LOG2E, a.w * C_LOG2E};
        wv[2 * h + 0] = (v2f){b.x, b.y};
        wv[2 * h + 1] = (v2f){b.z, b.w};
    }
#pragma unroll
    for (int j = 0; j < 4; ++j) {
        m[j] = (v2f){0.f, 0.f};
        v[j] = (v2f){0.f, 0.f};
    }

    const v2f lam2 = (v2f){lam, lam};
    const v2f c09 = (v2f){0.9f, 0.9f};
    const v2f c0999 = (v2f){0.999f, 0.999f};

    for (int rid = 0; rid < iters; ++rid) {
        // exp2(x') = exp(x), fused with the payoff dot (no max-shift)
        v2f e[4];
        v2f E2 = (v2f){0.f, 0.f}, EW2 = (v2f){0.f, 0.f};
#pragma unroll
        for (int j = 0; j < 4; ++j) {
            e[j] = (v2f){__builtin_amdgcn_exp2f(x[j].x),
                         __builtin_amdgcn_exp2f(x[j].y)};
            E2 += e[j];
            EW2 += e[j] * wv[j];  // v_pk_fma_f32
        }
        // hoisted off the post-reduction critical path
        v2f lx[4], m9[4], v9[4];
#pragma unroll
        for (int j = 0; j < 4; ++j) {
            lx[j] = lam2 * x[j];
            m9[j] = c09 * m[j];
            v9[j] = c0999 * v[j];
        }
        const v2f tot = blockRed1B(E2.x + E2.y, EW2.x + EW2.y,
                                   part[rid & 1], wid, lane);
        const float rE = __builtin_amdgcn_rcpf(tot.x);
        const float rEc = rE * C_LOG2E;
        const float frEc = (tot.y * rE) * rEc;
        const float2 ct = tab[rid];
        const v2f u2 = (v2f){rEc, rEc};
        const v2f fu2 = (v2f){frEc, frEc};
        const v2f ctx2 = (v2f){ct.x, ct.x};
        const v2f eps2 = (v2f){ct.y, ct.y};
#pragma unroll
        for (int j = 0; j < 4; ++j) {
            const v2f t = fu2 - wv[j] * u2;   // 1 pk_fma
            const v2f g = e[j] * t + lx[j];   // 1 pk_fma
            m[j] = m9[j] + g;                 // 1 pk_add (x10 scale)
            v[j] = v9[j] + g * g;             // 1 pk_fma (x1000 scale)
            const v2f ve = v[j] + eps2;       // 1 pk_add
            const v2f ir = (v2f){__builtin_amdgcn_rsqf(ve.x),
                                 __builtin_amdgcn_rsqf(ve.y)};
            x[j] = x[j] - (m[j] * ctx2) * ir; // pk_mul + pk_fma
        }
    }

    // ---- finalize: g = s*(w-f)/lam at final x; br = (x-g)+g ----
    {
        const int p = iters & 1;
        v2f e[4];
        v2f E2 = (v2f){0.f, 0.f}, EW2 = (v2f){0.f, 0.f};
#pragma unroll
        for (int j = 0; j < 4; ++j) {
            e[j] = (v2f){__builtin_amdgcn_exp2f(x[j].x),
                         __builtin_amdgcn_exp2f(x[j].y)};
            E2 += e[j];
            EW2 += e[j] * wv[j];
        }
        const v2f tot = blockRed1B(E2.x + E2.y, EW2.x + EW2.y, part[p],
                                   wid, lane);
        const float rE = 1.0f / tot.x;  // precise one-time
        const float f = tot.y * rE;

        const float invc = 1.0f / C_LOG2E;
        float br[8];
#pragma unroll
        for (int j = 0; j < 4; ++j) {
#pragma unroll
            for (int h = 0; h < 2; ++h) {
                const float ee = h ? e[j].y : e[j].x;
                const float ww = h ? wv[j].y : wv[j].x;
                const float xx = (h ? x[j].y : x[j].x) * invc;  // back to x
                const float s = ee * rE;
                const float g = (s * (ww - f)) / lam;  // one-time IEEE div
                br[2 * j + h] = (xx - g) + g;
            }
        }

        // r = softmax(br) . w  (precise exp for the one-time output)
        v2f E3 = (v2f){0.f, 0.f}, EW3 = (v2f){0.f, 0.f};
#pragma unroll
        for (int j = 0; j < 4; ++j) {
            const v2f eb = (v2f){__expf(br[2 * j]), __expf(br[2 * j + 1])};
            E3 += eb;
            EW3 += eb * wv[j];
        }
        const v2f tot3 = blockRed1B(E3.x + E3.y, EW3.x + EW3.y, part[p ^ 1],
                                    wid, lane);
        const float r = tot3.y / tot3.x;  // precise one-time

        if (tid == 0) out[0] = r;
#pragma unroll
        for (int k = 0; k < 8; ++k) out[1 + (tid << 3) + k] = br[k];
    }
}

extern "C" void kernel_launch(void* const* d_in, const int* in_sizes, int n_in,
                              void* d_out, int out_size, void* d_ws,
                              size_t ws_size, hipStream_t stream) {
    const float* logits = (const float*)d_in[0];   // (8192,)
    const float* P      = (const float*)d_in[1];   // (8192, 8192)
    const float* x0     = (const float*)d_in[2];   // (8192,)
    const float* lam    = (const float*)d_in[3];   // scalar
    const float* lr     = (const float*)d_in[4];   // scalar
    const int*   iters  = (const int*)d_in[5];     // scalar int
    float* out = (float*)d_out;                    // [0]=r, [1..8192]=br

    float* q = (float*)d_ws;   // 8192 floats
    float* w = q + N;          // 8192 floats

    softmax_q_kernel<<<1, 1024, 0, stream>>>(logits, q);
    matvec_kernel<<<N, 256, 0, stream>>>(P, q, w);
    adam_kernel<<<1, 1024, 0, stream>>>(w, x0, lam, lr, iters, out);
}

// Round 11
// 100.802 us; speedup vs baseline: 1.8460x; 1.0792x over previous
//
#include <hip/hip_runtime.h>
#include <math.h>

#define N 8192
#define C_LOG2E 1.4426950408889634f

typedef float v2f __attribute__((ext_vector_type(2)));

// ---------- DPP full-wave (64-lane) sum; result valid in lane 63 ----------
__device__ __forceinline__ float dppWaveRed(float v) {
    float t;
    t = __int_as_float(__builtin_amdgcn_update_dpp(
        0, __float_as_int(v), 0x111, 0xf, 0xf, true)); v += t;  // row_shr:1
    t = __int_as_float(__builtin_amdgcn_update_dpp(
        0, __float_as_int(v), 0x112, 0xf, 0xf, true)); v += t;  // row_shr:2
    t = __int_as_float(__builtin_amdgcn_update_dpp(
        0, __float_as_int(v), 0x114, 0xf, 0xf, true)); v += t;  // row_shr:4
    t = __int_as_float(__builtin_amdgcn_update_dpp(
        0, __float_as_int(v), 0x118, 0xf, 0xf, true)); v += t;  // row_shr:8
    t = __int_as_float(__builtin_amdgcn_update_dpp(
        0, __float_as_int(v), 0x142, 0xa, 0xf, false)); v += t; // bcast15
    t = __int_as_float(__builtin_amdgcn_update_dpp(
        0, __float_as_int(v), 0x143, 0xc, 0xf, false)); v += t; // bcast31
    return v;
}
// Inclusive 8-lane scan (within 16-lane row); lane 7 holds sum of lanes 0..7.
__device__ __forceinline__ float dppRowRed8(float v) {
    float t;
    t = __int_as_float(__builtin_amdgcn_update_dpp(
        0, __float_as_int(v), 0x111, 0xf, 0xf, true)); v += t;
    t = __int_as_float(__builtin_amdgcn_update_dpp(
        0, __float_as_int(v), 0x112, 0xf, 0xf, true)); v += t;
    t = __int_as_float(__builtin_amdgcn_update_dpp(
        0, __float_as_int(v), 0x114, 0xf, 0xf, true)); v += t;
    return v;
}
__device__ __forceinline__ float readlane7(float v) {
    return __uint_as_float(
        (unsigned)__builtin_amdgcn_readlane(__float_as_uint(v), 7));
}

// ---------- one-time shuffle reductions (softmax_q / matvec) ----------
__device__ __forceinline__ float waveRedSum(float v) {
#pragma unroll
    for (int o = 32; o; o >>= 1) v += __shfl_xor(v, o);
    return v;
}
__device__ __forceinline__ float waveRedMax(float v) {
#pragma unroll
    for (int o = 32; o; o >>= 1) v = fmaxf(v, __shfl_xor(v, o));
    return v;
}
__device__ __forceinline__ float blockRedSum(float v, float* buf, int tid) {
    v = waveRedSum(v);
    if ((tid & 63) == 0) buf[tid >> 6] = v;
    __syncthreads();
    float r = buf[0];
#pragma unroll
    for (int j = 1; j < 16; ++j) r += buf[j];
    return r;
}
__device__ __forceinline__ float blockRedMax(float v, float* buf, int tid) {
    v = waveRedMax(v);
    if ((tid & 63) == 0) buf[tid >> 6] = v;
    __syncthreads();
    float r = buf[0];
#pragma unroll
    for (int j = 1; j < 16; ++j) r = fmaxf(r, buf[j]);
    return r;
}

// ---------- kernel 1: q = softmax(logits) (one-time, precise) -------------
__global__ __launch_bounds__(1024) void softmax_q_kernel(
    const float* __restrict__ logits, float* __restrict__ q) {
    __shared__ float bufA[16], bufB[16];
    const int tid = threadIdx.x;
    float vals[8];
    float mx = -INFINITY;
#pragma unroll
    for (int k = 0; k < 8; ++k) {
        vals[k] = logits[tid + (k << 10)];
        mx = fmaxf(mx, vals[k]);
    }
    mx = blockRedMax(mx, bufA, tid);
    float E = 0.f;
#pragma unroll
    for (int k = 0; k < 8; ++k) {
        vals[k] = expf(vals[k] - mx);
        E += vals[k];
    }
    E = blockRedSum(E, bufB, tid);
#pragma unroll
    for (int k = 0; k < 8; ++k) q[tid + (k << 10)] = vals[k] / E;
}

// ---------- kernel 2: w = P @ q  (row-per-block matvec, HBM-roofline) -----
__global__ __launch_bounds__(256) void matvec_kernel(
    const float* __restrict__ P, const float* __restrict__ q,
    float* __restrict__ w) {
    const int row = blockIdx.x;
    const float4* __restrict__ Pr =
        reinterpret_cast<const float4*>(P + (size_t)row * N);
    const float4* __restrict__ q4 = reinterpret_cast<const float4*>(q);
    const int t = threadIdx.x;
    float acc = 0.f;
#pragma unroll
    for (int k = 0; k < 8; ++k) {
        float4 p = Pr[t + (k << 8)];
        float4 qq = q4[t + (k << 8)];
        acc = fmaf(p.x, qq.x, acc);
        acc = fmaf(p.y, qq.y, acc);
        acc = fmaf(p.z, qq.z, acc);
        acc = fmaf(p.w, qq.w, acc);
    }
    acc = waveRedSum(acc);
    __shared__ float lds[4];
    if ((t & 63) == 0) lds[t >> 6] = acc;
    __syncthreads();
    if (t == 0) w[row] = (lds[0] + lds[1]) + (lds[2] + lds[3]);
}

// ---------- exact f64 integer power (binary exponentiation) ----------
__device__ __forceinline__ double ipowd(double b, int e) {
    double r = 1.0;
    while (e) {
        if (e & 1) r *= b;
        b *= b;
        e >>= 1;
    }
    return r;
}

// ---------- adam: ONE-barrier block reduction, barrier-free tail ----------
// 8 waves: dppWaveRed -> lane63 writes part[wid] -> __syncthreads -> EVERY
// thread: one broadcast ds_read_b64 of part[lane&7], 3-step dppRowRed8,
// readlane(7) -> uniform totals. Deterministic; one barrier per call; the
// caller alternates parity buffers (write of slot p at call i+2 is ordered
// after barrier(i+1), after all reads of slot p at call i).
__device__ __forceinline__ v2f blockRed1B(float E, float EW, v2f* partp,
                                          int wid, int lane) {
    E = dppWaveRed(E);
    EW = dppWaveRed(EW);
    if (lane == 63) partp[wid] = (v2f){E, EW};
    __syncthreads();
    const v2f pv = partp[lane & 7];
    const float E8 = dppRowRed8(pv.x);
    const float W8 = dppRowRed8(pv.y);
    return (v2f){readlane7(E8), readlane7(W8)};
}

// ---------- kernel 3: Adam loop + implicit-gradient finalize --------------
// 512 threads, 8 waves (2/SIMD), one CU. Thread t owns elements
// [16t, 16t+16) as 8 float2 ext-vectors (packed fp32). Doubled per-thread
// ILP hides trans/LDS latency; half the barrier participants and a 3-step
// partial reduce shrink the per-iter reduce tail. State scaling as r5-r10:
//   x' = x*log2e (exp -> one v_exp_f32), m' = 10c*m, v' = 1000c^2*v;
//   step' = ctn * m' * rsq(v' + epsn2),
//   ctn = c*ct*sqrt(10), epsn2 = 1000*(c*eps_t)^2,
//   ct = lr*sqrt(d2)/d1, eps_t = 1e-8*sqrt(d2)   (exact f64 table).
__global__ __launch_bounds__(512) void adam_kernel(
    const float* __restrict__ w_g, const float* __restrict__ x0,
    const float* __restrict__ lam_p, const float* __restrict__ lr_p,
    const int* __restrict__ iters_p, float* __restrict__ out) {
    __shared__ v2f part[2][8];
    __shared__ float2 tab[128];  // (ctn, epsn2)

    const int tid = threadIdx.x;
    const int wid = tid >> 6;
    const int lane = tid & 63;
    const float lam = lam_p[0];
    const float lr = lr_p[0];
    const int iters = iters_p[0];

    // parallel exact bias-correction table (first read after iter-0 barrier)
    if (tid < iters && tid < 128) {
        const float d1 = (float)(1.0 - ipowd(0.9, tid + 1));
        const float d2 = (float)(1.0 - ipowd(0.999, tid + 1));
        const float sd2 = sqrtf(d2);
        const float ct = lr * sd2 / d1;
        const float se = C_LOG2E * 1e-8f * sd2;
        tab[tid] = make_float2(C_LOG2E * ct * sqrtf(10.f), 1000.f * se * se);
    }

    // ---- registers: blocked mapping, float4 loads; x kept log2e-scaled ----
    v2f x[8], m[8], v[8], wv[8];
    const float4* __restrict__ x04 = reinterpret_cast<const float4*>(x0);
    const float4* __restrict__ wg4 = reinterpret_cast<const float4*>(w_g);
#pragma unroll
    for (int h = 0; h < 4; ++h) {
        const float4 a = x04[(tid << 2) | h];
        const float4 b = wg4[(tid << 2) | h];
        x[2 * h + 0] = (v2f){a.x * C_LOG2E, a.y * C_LOG2E};
        x[2 * h + 1] = (v2f){a.z * C_LOG2E, a.w * C_LOG2E};
        wv[2 * h + 0] = (v2f){b.x, b.y};
        wv[2 * h + 1] = (v2f){b.z, b.w};
    }
#pragma unroll
    for (int j = 0; j < 8; ++j) {
        m[j] = (v2f){0.f, 0.f};
        v[j] = (v2f){0.f, 0.f};
    }

    const v2f lam2 = (v2f){lam, lam};
    const v2f c09 = (v2f){0.9f, 0.9f};
    const v2f c0999 = (v2f){0.999f, 0.999f};

    for (int rid = 0; rid < iters; ++rid) {
        // exp2(x') = exp(x), fused with the payoff dot (no max-shift)
        v2f e[8];
        v2f E2 = (v2f){0.f, 0.f}, EW2 = (v2f){0.f, 0.f};
#pragma unroll
        for (int j = 0; j < 8; ++j) {
            e[j] = (v2f){__builtin_amdgcn_exp2f(x[j].x),
                         __builtin_amdgcn_exp2f(x[j].y)};
            E2 += e[j];
            EW2 += e[j] * wv[j];  // v_pk_fma_f32
        }
        // hoisted off the post-reduction critical path
        v2f lx[8], m9[8], v9[8];
#pragma unroll
        for (int j = 0; j < 8; ++j) {
            lx[j] = lam2 * x[j];
            m9[j] = c09 * m[j];
            v9[j] = c0999 * v[j];
        }
        const v2f tot = blockRed1B(E2.x + E2.y, EW2.x + EW2.y,
                                   part[rid & 1], wid, lane);
        const float rE = __builtin_amdgcn_rcpf(tot.x);
        const float rEc = rE * C_LOG2E;
        const float frEc = (tot.y * rE) * rEc;
        const float2 ct = tab[rid];
        const v2f u2 = (v2f){rEc, rEc};
        const v2f fu2 = (v2f){frEc, frEc};
        const v2f ctx2 = (v2f){ct.x, ct.x};
        const v2f eps2 = (v2f){ct.y, ct.y};
#pragma unroll
        for (int j = 0; j < 8; ++j) {
            const v2f t = fu2 - wv[j] * u2;   // 1 pk_fma
            const v2f g = e[j] * t + lx[j];   // 1 pk_fma
            m[j] = m9[j] + g;                 // 1 pk_add (x10 scale)
            v[j] = v9[j] + g * g;             // 1 pk_fma (x1000 scale)
            const v2f ve = v[j] + eps2;       // 1 pk_add
            const v2f ir = (v2f){__builtin_amdgcn_rsqf(ve.x),
                                 __builtin_amdgcn_rsqf(ve.y)};
            x[j] = x[j] - (m[j] * ctx2) * ir; // pk_mul + pk_fma
        }
    }

    // ---- finalize: g = s*(w-f)/lam at final x; br = (x-g)+g ----
    {
        const int p = iters & 1;
        v2f e[8];
        v2f E2 = (v2f){0.f, 0.f}, EW2 = (v2f){0.f, 0.f};
#pragma unroll
        for (int j = 0; j < 8; ++j) {
            e[j] = (v2f){__builtin_amdgcn_exp2f(x[j].x),
                         __builtin_amdgcn_exp2f(x[j].y)};
            E2 += e[j];
            EW2 += e[j] * wv[j];
        }
        const v2f tot = blockRed1B(E2.x + E2.y, EW2.x + EW2.y, part[p],
                                   wid, lane);
        const float rE = 1.0f / tot.x;  // precise one-time
        const float f = tot.y * rE;

        const float invc = 1.0f / C_LOG2E;
        float br[16];
#pragma unroll
        for (int j = 0; j < 8; ++j) {
#pragma unroll
            for (int h = 0; h < 2; ++h) {
                const float ee = h ? e[j].y : e[j].x;
                const float ww = h ? wv[j].y : wv[j].x;
                const float xx = (h ? x[j].y : x[j].x) * invc;  // back to x
                const float s = ee * rE;
                const float g = (s * (ww - f)) / lam;  // one-time IEEE div
                br[2 * j + h] = (xx - g) + g;
            }
        }

        // r = softmax(br) . w  (precise exp for the one-time output)
        v2f E3 = (v2f){0.f, 0.f}, EW3 = (v2f){0.f, 0.f};
#pragma unroll
        for (int j = 0; j < 8; ++j) {
            const v2f eb = (v2f){__expf(br[2 * j]), __expf(br[2 * j + 1])};
            E3 += eb;
            EW3 += eb * wv[j];
        }
        const v2f tot3 = blockRed1B(E3.x + E3.y, EW3.x + EW3.y, part[p ^ 1],
                                    wid, lane);
        const float r = tot3.y / tot3.x;  // precise one-time

        if (tid == 0) out[0] = r;
#pragma unroll
        for (int k = 0; k < 16; ++k) out[1 + (tid << 4) + k] = br[k];
    }
}

extern "C" void kernel_launch(void* const* d_in, const int* in_sizes, int n_in,
                              void* d_out, int out_size, void* d_ws,
                              size_t ws_size, hipStream_t stream) {
    const float* logits = (const float*)d_in[0];   // (8192,)
    const float* P      = (const float*)d_in[1];   // (8192, 8192)
    const float* x0     = (const float*)d_in[2];   // (8192,)
    const float* lam    = (const float*)d_in[3];   // scalar
    const float* lr     = (const float*)d_in[4];   // scalar
    const int*   iters  = (const int*)d_in[5];     // scalar int
    float* out = (float*)d_out;                    // [0]=r, [1..8192]=br

    float* q = (float*)d_ws;   // 8192 floats
    float* w = q + N;          // 8192 floats

    softmax_q_kernel<<<1, 1024, 0, stream>>>(logits, q);
    matvec_kernel<<<N, 256, 0, stream>>>(P, q, w);
    adam_kernel<<<1, 512, 0, stream>>>(w, x0, lam, lr, iters, out);
}

// Round 12
// 97.231 us; speedup vs baseline: 1.9138x; 1.0367x over previous
//
#include <hip/hip_runtime.h>
#include <math.h>

#define N 8192
#define C_LOG2E 1.4426950408889634f

typedef float v2f __attribute__((ext_vector_type(2)));

// ---------- DPP full-wave (64-lane) sum; result valid in lane 63 ----------
__device__ __forceinline__ float dppWaveRed(float v) {
    float t;
    t = __int_as_float(__builtin_amdgcn_update_dpp(
        0, __float_as_int(v), 0x111, 0xf, 0xf, true)); v += t;  // row_shr:1
    t = __int_as_float(__builtin_amdgcn_update_dpp(
        0, __float_as_int(v), 0x112, 0xf, 0xf, true)); v += t;  // row_shr:2
    t = __int_as_float(__builtin_amdgcn_update_dpp(
        0, __float_as_int(v), 0x114, 0xf, 0xf, true)); v += t;  // row_shr:4
    t = __int_as_float(__builtin_amdgcn_update_dpp(
        0, __float_as_int(v), 0x118, 0xf, 0xf, true)); v += t;  // row_shr:8
    t = __int_as_float(__builtin_amdgcn_update_dpp(
        0, __float_as_int(v), 0x142, 0xa, 0xf, false)); v += t; // bcast15
    t = __int_as_float(__builtin_amdgcn_update_dpp(
        0, __float_as_int(v), 0x143, 0xc, 0xf, false)); v += t; // bcast31
    return v;
}

// ---------- one-time shuffle reductions (softmax_q / matvec) ----------
__device__ __forceinline__ float waveRedSum(float v) {
#pragma unroll
    for (int o = 32; o; o >>= 1) v += __shfl_xor(v, o);
    return v;
}
__device__ __forceinline__ float waveRedMax(float v) {
#pragma unroll
    for (int o = 32; o; o >>= 1) v = fmaxf(v, __shfl_xor(v, o));
    return v;
}
__device__ __forceinline__ float blockRedSum(float v, float* buf, int tid) {
    v = waveRedSum(v);
    if ((tid & 63) == 0) buf[tid >> 6] = v;
    __syncthreads();
    float r = buf[0];
#pragma unroll
    for (int j = 1; j < 16; ++j) r += buf[j];
    return r;
}
__device__ __forceinline__ float blockRedMax(float v, float* buf, int tid) {
    v = waveRedMax(v);
    if ((tid & 63) == 0) buf[tid >> 6] = v;
    __syncthreads();
    float r = buf[0];
#pragma unroll
    for (int j = 1; j < 16; ++j) r = fmaxf(r, buf[j]);
    return r;
}

// ---------- kernel 1: q = softmax(logits) (one-time, precise) -------------
__global__ __launch_bounds__(1024) void softmax_q_kernel(
    const float* __restrict__ logits, float* __restrict__ q) {
    __shared__ float bufA[16], bufB[16];
    const int tid = threadIdx.x;
    float vals[8];
    float mx = -INFINITY;
#pragma unroll
    for (int k = 0; k < 8; ++k) {
        vals[k] = logits[tid + (k << 10)];
        mx = fmaxf(mx, vals[k]);
    }
    mx = blockRedMax(mx, bufA, tid);
    float E = 0.f;
#pragma unroll
    for (int k = 0; k < 8; ++k) {
        vals[k] = expf(vals[k] - mx);
        E += vals[k];
    }
    E = blockRedSum(E, bufB, tid);
#pragma unroll
    for (int k = 0; k < 8; ++k) q[tid + (k << 10)] = vals[k] / E;
}

// ---------- kernel 2: w = P @ q  (row-per-block matvec, HBM-roofline) -----
__global__ __launch_bounds__(256) void matvec_kernel(
    const float* __restrict__ P, const float* __restrict__ q,
    float* __restrict__ w) {
    const int row = blockIdx.x;
    const float4* __restrict__ Pr =
        reinterpret_cast<const float4*>(P + (size_t)row * N);
    const float4* __restrict__ q4 = reinterpret_cast<const float4*>(q);
    const int t = threadIdx.x;
    float acc = 0.f;
#pragma unroll
    for (int k = 0; k < 8; ++k) {
        float4 p = Pr[t + (k << 8)];
        float4 qq = q4[t + (k << 8)];
        acc = fmaf(p.x, qq.x, acc);
        acc = fmaf(p.y, qq.y, acc);
        acc = fmaf(p.z, qq.z, acc);
        acc = fmaf(p.w, qq.w, acc);
    }
    acc = waveRedSum(acc);
    __shared__ float lds[4];
    if ((t & 63) == 0) lds[t >> 6] = acc;
    __syncthreads();
    if (t == 0) w[row] = (lds[0] + lds[1]) + (lds[2] + lds[3]);
}

// ---------- exact f64 integer power (binary exponentiation) ----------
__device__ __forceinline__ double ipowd(double b, int e) {
    double r = 1.0;
    while (e) {
        if (e & 1) r *= b;
        b *= b;
        e >>= 1;
    }
    return r;
}

// ---------- adam: ONE-barrier 4-wave reduction, 2-LDS-read tail -----------
// dppWaveRed -> lane63 writes part[wid] (4 partials, 32B) -> __syncthreads
// -> EVERY thread reads the 4 partials as 2 broadcast ds_read_b128 and
// does 3 pk-adds. No DPP tail, no readlane. Deterministic (fixed order).
// Race safety with ONE barrier/call: caller alternates parity buffers; a
// write to slot p at call i+2 happens after barrier(i+1), which orders it
// after all reads of slot p at call i.
__device__ __forceinline__ v2f blockRed1B(float E, float EW, v2f* partp,
                                          int wid, int lane) {
    E = dppWaveRed(E);
    EW = dppWaveRed(EW);
    if (lane == 63) partp[wid] = (v2f){E, EW};
    __syncthreads();
    const float4* p4 = reinterpret_cast<const float4*>(partp);
    const float4 q0 = p4[0], q1 = p4[1];
    const v2f a = (v2f){q0.x, q0.y} + (v2f){q0.z, q0.w};
    const v2f b = (v2f){q1.x, q1.y} + (v2f){q1.z, q1.w};
    return a + b;
}

// ---------- kernel 3: Adam loop + implicit-gradient finalize --------------
// 256 threads, 4 waves (1/SIMD), one CU. Thread t owns elements
// [32t, 32t+32) as 16 float2 ext-vectors (packed fp32). Minimum-width
// barrier (4 waves), minimum tail (2 broadcast LDS reads + 3 pk adds),
// 32-deep per-thread ILP saturates the trans pipe. State scaling as
// r5-r11:
//   x' = x*log2e (exp -> one v_exp_f32), m' = 10c*m, v' = 1000c^2*v;
//   step' = ctn * m' * rsq(v' + epsn2),
//   ctn = c*ct*sqrt(10), epsn2 = 1000*(c*eps_t)^2,
//   ct = lr*sqrt(d2)/d1, eps_t = 1e-8*sqrt(d2)   (exact f64 table).
__global__ __launch_bounds__(256, 1) void adam_kernel(
    const float* __restrict__ w_g, const float* __restrict__ x0,
    const float* __restrict__ lam_p, const float* __restrict__ lr_p,
    const int* __restrict__ iters_p, float* __restrict__ out) {
    __shared__ alignas(16) v2f part[2][4];
    __shared__ float2 tab[128];  // (ctn, epsn2)

    const int tid = threadIdx.x;
    const int wid = tid >> 6;
    const int lane = tid & 63;
    const float lam = lam_p[0];
    const float lr = lr_p[0];
    const int iters = iters_p[0];

    // parallel exact bias-correction table (first read after iter-0 barrier)
    if (tid < iters && tid < 128) {
        const float d1 = (float)(1.0 - ipowd(0.9, tid + 1));
        const float d2 = (float)(1.0 - ipowd(0.999, tid + 1));
        const float sd2 = sqrtf(d2);
        const float ct = lr * sd2 / d1;
        const float se = C_LOG2E * 1e-8f * sd2;
        tab[tid] = make_float2(C_LOG2E * ct * sqrtf(10.f), 1000.f * se * se);
    }

    // ---- registers: blocked mapping, float4 loads; x kept log2e-scaled ----
    v2f x[16], m[16], v[16], wv[16];
    const float4* __restrict__ x04 = reinterpret_cast<const float4*>(x0);
    const float4* __restrict__ wg4 = reinterpret_cast<const float4*>(w_g);
#pragma unroll
    for (int h = 0; h < 8; ++h) {
        const float4 a = x04[(tid << 3) | h];
        const float4 b = wg4[(tid << 3) | h];
        x[2 * h + 0] = (v2f){a.x * C_LOG2E, a.y * C_LOG2E};
        x[2 * h + 1] = (v2f){a.z * C_LOG2E, a.w * C_LOG2E};
        wv[2 * h + 0] = (v2f){b.x, b.y};
        wv[2 * h + 1] = (v2f){b.z, b.w};
    }
#pragma unroll
    for (int j = 0; j < 16; ++j) {
        m[j] = (v2f){0.f, 0.f};
        v[j] = (v2f){0.f, 0.f};
    }

    const v2f lam2 = (v2f){lam, lam};
    const v2f c09 = (v2f){0.9f, 0.9f};
    const v2f c0999 = (v2f){0.999f, 0.999f};

    for (int rid = 0; rid < iters; ++rid) {
        // hoisted LDS read: completes under the reduction barrier
        const float2 ct = tab[rid];
        // exp2(x') = exp(x), fused with the payoff dot (no max-shift)
        v2f e[16];
        v2f E2 = (v2f){0.f, 0.f}, EW2 = (v2f){0.f, 0.f};
#pragma unroll
        for (int j = 0; j < 16; ++j) {
            e[j] = (v2f){__builtin_amdgcn_exp2f(x[j].x),
                         __builtin_amdgcn_exp2f(x[j].y)};
            E2 += e[j];
            EW2 += e[j] * wv[j];  // v_pk_fma_f32
        }
        const v2f tot = blockRed1B(E2.x + E2.y, EW2.x + EW2.y,
                                   part[rid & 1], wid, lane);
        const float rE = __builtin_amdgcn_rcpf(tot.x);
        const float rEc = rE * C_LOG2E;
        const float frEc = (tot.y * rE) * rEc;
        const v2f u2 = (v2f){rEc, rEc};
        const v2f fu2 = (v2f){frEc, frEc};
        const v2f ctx2 = (v2f){ct.x, ct.x};
        const v2f eps2 = (v2f){ct.y, ct.y};
#pragma unroll
        for (int j = 0; j < 16; ++j) {
            const v2f t = fu2 - wv[j] * u2;    // 1 pk_fma
            const v2f g = e[j] * t + lam2 * x[j];  // pk_mul + pk_fma
            m[j] = c09 * m[j] + g;             // 1 pk_fma (x10 scale)
            v[j] = c0999 * v[j] + g * g;       // pk_mul + pk_fma (x1000)
            const v2f ve = v[j] + eps2;        // 1 pk_add
            const v2f ir = (v2f){__builtin_amdgcn_rsqf(ve.x),
                                 __builtin_amdgcn_rsqf(ve.y)};
            x[j] = x[j] - (m[j] * ctx2) * ir;  // pk_mul + pk_fma
        }
    }

    // ---- finalize: g = s*(w-f)/lam at final x; br = (x-g)+g ----
    {
        const int p = iters & 1;
        v2f e[16];
        v2f E2 = (v2f){0.f, 0.f}, EW2 = (v2f){0.f, 0.f};
#pragma unroll
        for (int j = 0; j < 16; ++j) {
            e[j] = (v2f){__builtin_amdgcn_exp2f(x[j].x),
                         __builtin_amdgcn_exp2f(x[j].y)};
            E2 += e[j];
            EW2 += e[j] * wv[j];
        }
        const v2f tot = blockRed1B(E2.x + E2.y, EW2.x + EW2.y, part[p],
                                   wid, lane);
        const float rE = 1.0f / tot.x;  // precise one-time
        const float f = tot.y * rE;

        const float invc = 1.0f / C_LOG2E;
        float br[32];
#pragma unroll
        for (int j = 0; j < 16; ++j) {
#pragma unroll
            for (int h = 0; h < 2; ++h) {
                const float ee = h ? e[j].y : e[j].x;
                const float ww = h ? wv[j].y : wv[j].x;
                const float xx = (h ? x[j].y : x[j].x) * invc;  // back to x
                const float s = ee * rE;
                const float g = (s * (ww - f)) / lam;  // one-time IEEE div
                br[2 * j + h] = (xx - g) + g;
            }
        }

        // r = softmax(br) . w  (precise exp for the one-time output)
        v2f E3 = (v2f){0.f, 0.f}, EW3 = (v2f){0.f, 0.f};
#pragma unroll
        for (int j = 0; j < 16; ++j) {
            const v2f eb = (v2f){__expf(br[2 * j]), __expf(br[2 * j + 1])};
            E3 += eb;
            EW3 += eb * wv[j];
        }
        const v2f tot3 = blockRed1B(E3.x + E3.y, EW3.x + EW3.y, part[p ^ 1],
                                    wid, lane);
        const float r = tot3.y / tot3.x;  // precise one-time

        if (tid == 0) out[0] = r;
#pragma unroll
        for (int k = 0; k < 32; ++k) out[1 + (tid << 5) + k] = br[k];
    }
}

extern "C" void kernel_launch(void* const* d_in, const int* in_sizes, int n_in,
                              void* d_out, int out_size, void* d_ws,
                              size_t ws_size, hipStream_t stream) {
    const float* logits = (const float*)d_in[0];   // (8192,)
    const float* P      = (const float*)d_in[1];   // (8192, 8192)
    const float* x0     = (const float*)d_in[2];   // (8192,)
    const float* lam    = (const float*)d_in[3];   // scalar
    const float* lr     = (const float*)d_in[4];   // scalar
    const int*   iters  = (const int*)d_in[5];     // scalar int
    float* out = (float*)d_out;                    // [0]=r, [1..8192]=br

    float* q = (float*)d_ws;   // 8192 floats
    float* w = q + N;          // 8192 floats

    softmax_q_kernel<<<1, 1024, 0, stream>>>(logits, q);
    matvec_kernel<<<N, 256, 0, stream>>>(P, q, w);
    adam_kernel<<<1, 256, 0, stream>>>(w, x0, lam, lr, iters, out);
}

// Round 13
// 96.840 us; speedup vs baseline: 1.9215x; 1.0040x over previous
//
#include <hip/hip_runtime.h>
#include <math.h>

#define N 8192
#define C_LOG2E 1.4426950408889634f

typedef float v2f __attribute__((ext_vector_type(2)));

// ---------- DPP full-wave (64-lane) sum; result valid in lane 63 ----------
__device__ __forceinline__ float dppWaveRed(float v) {
    float t;
    t = __int_as_float(__builtin_amdgcn_update_dpp(
        0, __float_as_int(v), 0x111, 0xf, 0xf, true)); v += t;  // row_shr:1
    t = __int_as_float(__builtin_amdgcn_update_dpp(
        0, __float_as_int(v), 0x112, 0xf, 0xf, true)); v += t;  // row_shr:2
    t = __int_as_float(__builtin_amdgcn_update_dpp(
        0, __float_as_int(v), 0x114, 0xf, 0xf, true)); v += t;  // row_shr:4
    t = __int_as_float(__builtin_amdgcn_update_dpp(
        0, __float_as_int(v), 0x118, 0xf, 0xf, true)); v += t;  // row_shr:8
    t = __int_as_float(__builtin_amdgcn_update_dpp(
        0, __float_as_int(v), 0x142, 0xa, 0xf, false)); v += t; // bcast15
    t = __int_as_float(__builtin_amdgcn_update_dpp(
        0, __float_as_int(v), 0x143, 0xc, 0xf, false)); v += t; // bcast31
    return v;
}

// ---------- one-time shuffle reductions (softmax_q / matvec) ----------
__device__ __forceinline__ float waveRedSum(float v) {
#pragma unroll
    for (int o = 32; o; o >>= 1) v += __shfl_xor(v, o);
    return v;
}
__device__ __forceinline__ float waveRedMax(float v) {
#pragma unroll
    for (int o = 32; o; o >>= 1) v = fmaxf(v, __shfl_xor(v, o));
    return v;
}
__device__ __forceinline__ float blockRedSum(float v, float* buf, int tid) {
    v = waveRedSum(v);
    if ((tid & 63) == 0) buf[tid >> 6] = v;
    __syncthreads();
    float r = buf[0];
#pragma unroll
    for (int j = 1; j < 16; ++j) r += buf[j];
    return r;
}
__device__ __forceinline__ float blockRedMax(float v, float* buf, int tid) {
    v = waveRedMax(v);
    if ((tid & 63) == 0) buf[tid >> 6] = v;
    __syncthreads();
    float r = buf[0];
#pragma unroll
    for (int j = 1; j < 16; ++j) r = fmaxf(r, buf[j]);
    return r;
}

// ---------- kernel 1: q = softmax(logits) (one-time, precise) -------------
__global__ __launch_bounds__(1024) void softmax_q_kernel(
    const float* __restrict__ logits, float* __restrict__ q) {
    __shared__ float bufA[16], bufB[16];
    const int tid = threadIdx.x;
    float vals[8];
    float mx = -INFINITY;
#pragma unroll
    for (int k = 0; k < 8; ++k) {
        vals[k] = logits[tid + (k << 10)];
        mx = fmaxf(mx, vals[k]);
    }
    mx = blockRedMax(mx, bufA, tid);
    float E = 0.f;
#pragma unroll
    for (int k = 0; k < 8; ++k) {
        vals[k] = expf(vals[k] - mx);
        E += vals[k];
    }
    E = blockRedSum(E, bufB, tid);
#pragma unroll
    for (int k = 0; k < 8; ++k) q[tid + (k << 10)] = vals[k] / E;
}

// ---------- kernel 2: w = P @ q  (row-per-block matvec, HBM-roofline) -----
__global__ __launch_bounds__(256) void matvec_kernel(
    const float* __restrict__ P, const float* __restrict__ q,
    float* __restrict__ w) {
    const int row = blockIdx.x;
    const float4* __restrict__ Pr =
        reinterpret_cast<const float4*>(P + (size_t)row * N);
    const float4* __restrict__ q4 = reinterpret_cast<const float4*>(q);
    const int t = threadIdx.x;
    float acc = 0.f;
#pragma unroll
    for (int k = 0; k < 8; ++k) {
        float4 p = Pr[t + (k << 8)];
        float4 qq = q4[t + (k << 8)];
        acc = fmaf(p.x, qq.x, acc);
        acc = fmaf(p.y, qq.y, acc);
        acc = fmaf(p.z, qq.z, acc);
        acc = fmaf(p.w, qq.w, acc);
    }
    acc = waveRedSum(acc);
    __shared__ float lds[4];
    if ((t & 63) == 0) lds[t >> 6] = acc;
    __syncthreads();
    if (t == 0) w[row] = (lds[0] + lds[1]) + (lds[2] + lds[3]);
}

// ---------- exact f64 integer power (binary exponentiation) ----------
__device__ __forceinline__ double ipowd(double b, int e) {
    double r = 1.0;
    while (e) {
        if (e & 1) r *= b;
        b *= b;
        e >>= 1;
    }
    return r;
}

// ---------- adam: ONE-barrier 4-wave reduction, 2-LDS-read tail -----------
// dppWaveRed -> lane63 writes part[wid] (4 partials, 32B) -> __syncthreads
// -> EVERY thread reads the 4 partials as 2 broadcast ds_read_b128 and
// does 3 pk-adds. No DPP tail, no readlane. Deterministic (fixed order).
// Race safety with ONE barrier/call: caller alternates parity buffers; a
// write to slot p at call i+2 happens after barrier(i+1), which orders it
// after all reads of slot p at call i.
__device__ __forceinline__ v2f blockRed1B(float E, float EW, v2f* partp,
                                          int wid, int lane) {
    E = dppWaveRed(E);
    EW = dppWaveRed(EW);
    if (lane == 63) partp[wid] = (v2f){E, EW};
    __syncthreads();
    const float4* p4 = reinterpret_cast<const float4*>(partp);
    const float4 q0 = p4[0], q1 = p4[1];
    const v2f a = (v2f){q0.x, q0.y} + (v2f){q0.z, q0.w};
    const v2f b = (v2f){q1.x, q1.y} + (v2f){q1.z, q1.w};
    return a + b;
}

// ---------- kernel 3: Adam loop + implicit-gradient finalize --------------
// 256 threads, 4 waves (1/SIMD), one CU. Thread t owns elements
// [32t, 32t+32) as 16 float2 ext-vectors (packed fp32).
// Critical-path surgery this round:
//  - E2/EW2 built with 4 parallel accumulator chains + tree combine
//    (depth 16 -> ~6) so the DPP reduce starts ~100 cyc earlier;
//  - lam*x / 0.9*m / 0.999*v hoisted BEFORE the reduction call: those 96
//    pk-insts issue into the barrier + ds_read stall shadow.
// State scaling as r5-r12:
//   x' = x*log2e (exp -> one v_exp_f32), m' = 10c*m, v' = 1000c^2*v;
//   step' = ctn * m' * rsq(v' + epsn2),
//   ctn = c*ct*sqrt(10), epsn2 = 1000*(c*eps_t)^2,
//   ct = lr*sqrt(d2)/d1, eps_t = 1e-8*sqrt(d2)   (exact f64 table).
__global__ __launch_bounds__(256, 1) void adam_kernel(
    const float* __restrict__ w_g, const float* __restrict__ x0,
    const float* __restrict__ lam_p, const float* __restrict__ lr_p,
    const int* __restrict__ iters_p, float* __restrict__ out) {
    __shared__ alignas(16) v2f part[2][4];
    __shared__ float2 tab[128];  // (ctn, epsn2)

    const int tid = threadIdx.x;
    const int wid = tid >> 6;
    const int lane = tid & 63;
    const float lam = lam_p[0];
    const float lr = lr_p[0];
    const int iters = iters_p[0];

    // parallel exact bias-correction table (first read after iter-0 barrier)
    if (tid < iters && tid < 128) {
        const float d1 = (float)(1.0 - ipowd(0.9, tid + 1));
        const float d2 = (float)(1.0 - ipowd(0.999, tid + 1));
        const float sd2 = sqrtf(d2);
        const float ct = lr * sd2 / d1;
        const float se = C_LOG2E * 1e-8f * sd2;
        tab[tid] = make_float2(C_LOG2E * ct * sqrtf(10.f), 1000.f * se * se);
    }

    // ---- registers: blocked mapping, float4 loads; x kept log2e-scaled ----
    v2f x[16], m[16], v[16], wv[16];
    const float4* __restrict__ x04 = reinterpret_cast<const float4*>(x0);
    const float4* __restrict__ wg4 = reinterpret_cast<const float4*>(w_g);
#pragma unroll
    for (int h = 0; h < 8; ++h) {
        const float4 a = x04[(tid << 3) | h];
        const float4 b = wg4[(tid << 3) | h];
        x[2 * h + 0] = (v2f){a.x * C_LOG2E, a.y * C_LOG2E};
        x[2 * h + 1] = (v2f){a.z * C_LOG2E, a.w * C_LOG2E};
        wv[2 * h + 0] = (v2f){b.x, b.y};
        wv[2 * h + 1] = (v2f){b.z, b.w};
    }
#pragma unroll
    for (int j = 0; j < 16; ++j) {
        m[j] = (v2f){0.f, 0.f};
        v[j] = (v2f){0.f, 0.f};
    }

    const v2f lam2 = (v2f){lam, lam};
    const v2f c09 = (v2f){0.9f, 0.9f};
    const v2f c0999 = (v2f){0.999f, 0.999f};
    const v2f z2 = (v2f){0.f, 0.f};

    for (int rid = 0; rid < iters; ++rid) {
        // hoisted LDS read: completes under the reduction barrier
        const float2 ct = tab[rid];
        // exp2(x') = exp(x); E/EW via 4 parallel accumulator chains
        v2f e[16];
        v2f Ea[4] = {z2, z2, z2, z2};
        v2f Wa[4] = {z2, z2, z2, z2};
#pragma unroll
        for (int j = 0; j < 16; ++j) {
            e[j] = (v2f){__builtin_amdgcn_exp2f(x[j].x),
                         __builtin_amdgcn_exp2f(x[j].y)};
            Ea[j & 3] += e[j];
            Wa[j & 3] += e[j] * wv[j];  // v_pk_fma_f32
        }
        const v2f E2 = (Ea[0] + Ea[1]) + (Ea[2] + Ea[3]);
        const v2f EW2 = (Wa[0] + Wa[1]) + (Wa[2] + Wa[3]);
        // hoisted off the post-reduction critical path: these 96 pk-insts
        // issue while the wave stalls on barrier + broadcast ds_read.
        v2f lx[16], m9[16], v9[16];
#pragma unroll
        for (int j = 0; j < 16; ++j) {
            lx[j] = lam2 * x[j];
            m9[j] = c09 * m[j];
            v9[j] = c0999 * v[j];
        }
        const v2f tot = blockRed1B(E2.x + E2.y, EW2.x + EW2.y,
                                   part[rid & 1], wid, lane);
        const float rE = __builtin_amdgcn_rcpf(tot.x);
        const float rEc = rE * C_LOG2E;
        const float frEc = (tot.y * rE) * rEc;
        const v2f u2 = (v2f){rEc, rEc};
        const v2f fu2 = (v2f){frEc, frEc};
        const v2f ctx2 = (v2f){ct.x, ct.x};
        const v2f eps2 = (v2f){ct.y, ct.y};
#pragma unroll
        for (int j = 0; j < 16; ++j) {
            const v2f t = fu2 - wv[j] * u2;   // 1 pk_fma
            const v2f g = e[j] * t + lx[j];   // 1 pk_fma
            m[j] = m9[j] + g;                 // 1 pk_add (x10 scale)
            v[j] = v9[j] + g * g;             // 1 pk_fma (x1000 scale)
            const v2f ve = v[j] + eps2;       // 1 pk_add
            const v2f ir = (v2f){__builtin_amdgcn_rsqf(ve.x),
                                 __builtin_amdgcn_rsqf(ve.y)};
            x[j] = x[j] - (m[j] * ctx2) * ir; // pk_mul + pk_fma
        }
    }

    // ---- finalize: g = s*(w-f)/lam at final x; br = (x-g)+g ----
    {
        const int p = iters & 1;
        v2f e[16];
        v2f Ea[4] = {z2, z2, z2, z2};
        v2f Wa[4] = {z2, z2, z2, z2};
#pragma unroll
        for (int j = 0; j < 16; ++j) {
            e[j] = (v2f){__builtin_amdgcn_exp2f(x[j].x),
                         __builtin_amdgcn_exp2f(x[j].y)};
            Ea[j & 3] += e[j];
            Wa[j & 3] += e[j] * wv[j];
        }
        const v2f E2 = (Ea[0] + Ea[1]) + (Ea[2] + Ea[3]);
        const v2f EW2 = (Wa[0] + Wa[1]) + (Wa[2] + Wa[3]);
        const v2f tot = blockRed1B(E2.x + E2.y, EW2.x + EW2.y, part[p],
                                   wid, lane);
        const float rE = 1.0f / tot.x;  // precise one-time
        const float f = tot.y * rE;

        const float invc = 1.0f / C_LOG2E;
        float br[32];
#pragma unroll
        for (int j = 0; j < 16; ++j) {
#pragma unroll
            for (int h = 0; h < 2; ++h) {
                const float ee = h ? e[j].y : e[j].x;
                const float ww = h ? wv[j].y : wv[j].x;
                const float xx = (h ? x[j].y : x[j].x) * invc;  // back to x
                const float s = ee * rE;
                const float g = (s * (ww - f)) / lam;  // one-time IEEE div
                br[2 * j + h] = (xx - g) + g;
            }
        }

        // r = softmax(br) . w  (precise exp for the one-time output)
        v2f E3 = z2, EW3 = z2;
#pragma unroll
        for (int j = 0; j < 16; ++j) {
            const v2f eb = (v2f){__expf(br[2 * j]), __expf(br[2 * j + 1])};
            E3 += eb;
            EW3 += eb * wv[j];
        }
        const v2f tot3 = blockRed1B(E3.x + E3.y, EW3.x + EW3.y, part[p ^ 1],
                                    wid, lane);
        const float r = tot3.y / tot3.x;  // precise one-time

        if (tid == 0) out[0] = r;
#pragma unroll
        for (int k = 0; k < 32; ++k) out[1 + (tid << 5) + k] = br[k];
    }
}

extern "C" void kernel_launch(void* const* d_in, const int* in_sizes, int n_in,
                              void* d_out, int out_size, void* d_ws,
                              size_t ws_size, hipStream_t stream) {
    const float* logits = (const float*)d_in[0];   // (8192,)
    const float* P      = (const float*)d_in[1];   // (8192, 8192)
    const float* x0     = (const float*)d_in[2];   // (8192,)
    const float* lam    = (const float*)d_in[3];   // scalar
    const float* lr     = (const float*)d_in[4];   // scalar
    const int*   iters  = (const int*)d_in[5];     // scalar int
    float* out = (float*)d_out;                    // [0]=r, [1..8192]=br

    float* q = (float*)d_ws;   // 8192 floats
    float* w = q + N;          // 8192 floats

    softmax_q_kernel<<<1, 1024, 0, stream>>>(logits, q);
    matvec_kernel<<<N, 256, 0, stream>>>(P, q, w);
    adam_kernel<<<1, 256, 0, stream>>>(w, x0, lam, lr, iters, out);
}